// Round 9
// baseline (60.584 us; speedup 1.0000x reference)
//
#include <hip/hip_runtime.h>
#include <stdint.h>

#define V 128000
#define NROWS 128
#define NSG 25                // gather slices per row
#define SG_ELEMS (V / NSG)    // 5120 -> exactly 5 float4 per thread at 256 thr
#define NF4 (SG_ELEMS / 4)    // 1280 float4 per slice
#define UNR 5                 // float4 per thread per array
#define SCAP 256              // per-slice candidate capacity (~117 expected, 13 sigma)
#define CAPK (NSG * SCAP)     // 6400 max candidates per row
#define SELK 2048             // post-select capacity (>= k_max + boundary bin)
#define ZCAP 1024
#define NBINS 4096
#define THRESH 8.0f           // static prefilter: ~2912 cands/row, k<=1023 w/ 35-sigma margin

typedef unsigned long long ull;

__device__ __forceinline__ uint32_t f2key(uint32_t b) {
    // monotone map: float bits -> orderable uint32
    return (b & 0x80000000u) ? ~b : (b | 0x80000000u);
}
__device__ __forceinline__ float key2f(uint32_t u) {
    uint32_t b = (u & 0x80000000u) ? (u & 0x7FFFFFFFu) : ~u;
    return __uint_as_float(b);
}

// ---- K1: fused gather (logits >= THRESH) + q==0 exact-zero scan -------------
// All 10 global loads issued back-to-back per thread (max MLP), then process
// from registers.
__global__ __launch_bounds__(256) void k_gather(const float* __restrict__ logits,
                                                const float* __restrict__ q,
                                                uint32_t* __restrict__ scnt,
                                                ull* __restrict__ list,
                                                uint32_t* __restrict__ zcnt,
                                                ull* __restrict__ zlist) {
    __shared__ ull lbuf[SCAP];
    __shared__ uint32_t lcnt;
    const int row = blockIdx.x / NSG;
    const int slice = blockIdx.x % NSG;
    const int t = threadIdx.x;
    if (t == 0) lcnt = 0;
    __syncthreads();

    const float4* lb = (const float4*)(logits + (size_t)row * V + (size_t)slice * SG_ELEMS);
    const float4* qb = (const float4*)(q + (size_t)row * V + (size_t)slice * SG_ELEMS);

    float4 lv[UNR], qv[UNR];
#pragma unroll
    for (int u = 0; u < UNR; ++u) lv[u] = lb[t + 256 * u];
#pragma unroll
    for (int u = 0; u < UNR; ++u) qv[u] = qb[t + 256 * u];

#pragma unroll
    for (int u = 0; u < UNR; ++u) {
        const int bidx = slice * SG_ELEMS + (t + 256 * u) * 4;
        const float4 v = lv[u];
        if (v.x >= THRESH) { unsigned p = atomicAdd(&lcnt, 1u); if (p < SCAP) lbuf[p] = ((ull)f2key(__float_as_uint(v.x)) << 32) | (unsigned)(bidx + 0); }
        if (v.y >= THRESH) { unsigned p = atomicAdd(&lcnt, 1u); if (p < SCAP) lbuf[p] = ((ull)f2key(__float_as_uint(v.y)) << 32) | (unsigned)(bidx + 1); }
        if (v.z >= THRESH) { unsigned p = atomicAdd(&lcnt, 1u); if (p < SCAP) lbuf[p] = ((ull)f2key(__float_as_uint(v.z)) << 32) | (unsigned)(bidx + 2); }
        if (v.w >= THRESH) { unsigned p = atomicAdd(&lcnt, 1u); if (p < SCAP) lbuf[p] = ((ull)f2key(__float_as_uint(v.w)) << 32) | (unsigned)(bidx + 3); }
        // q == 0 exact-zero scan (reference: probs/q = 0/0 = NaN at masked pos;
        // np.argmax returns first NaN index). ~2 hits expected globally.
        const float4 w = qv[u];
        if (w.x == 0.f) { unsigned p0 = atomicAdd(zcnt, 1u); if (p0 < ZCAP) zlist[p0] = ((ull)row << 32) | (unsigned)(bidx + 0); }
        if (w.y == 0.f) { unsigned p0 = atomicAdd(zcnt, 1u); if (p0 < ZCAP) zlist[p0] = ((ull)row << 32) | (unsigned)(bidx + 1); }
        if (w.z == 0.f) { unsigned p0 = atomicAdd(zcnt, 1u); if (p0 < ZCAP) zlist[p0] = ((ull)row << 32) | (unsigned)(bidx + 2); }
        if (w.w == 0.f) { unsigned p0 = atomicAdd(zcnt, 1u); if (p0 < ZCAP) zlist[p0] = ((ull)row << 32) | (unsigned)(bidx + 3); }
    }
    __syncthreads();
    uint32_t c = min(lcnt, (uint32_t)SCAP);
    ull* seg = list + (size_t)(row * NSG + slice) * SCAP;
    for (int i = t; i < (int)c; i += 256) seg[i] = lbuf[i];
    if (t == 0) scnt[row * NSG + slice] = c;
}

// ---- K2: per-row counting-sort select + thresholds + exp-race argmax --------
__global__ __launch_bounds__(1024) void k_final(const ull* __restrict__ list,
                                                const uint32_t* __restrict__ scnt,
                                                const int* __restrict__ kk,
                                                const float* __restrict__ pp,
                                                const float* __restrict__ q,
                                                const float* __restrict__ logits,
                                                const ull* __restrict__ zlist,
                                                const uint32_t* __restrict__ zcnt,
                                                int* __restrict__ out) {
    __shared__ ull cand[CAPK];          // 51.2 KB
    __shared__ ull skeys[SELK];         // 16 KB
    __shared__ uint32_t hist[NBINS];    // 16 KB (reused: counts -> scatter cursors)
    __shared__ uint32_t binoff[NBINS];  // 16 KB (segment start offsets)
    __shared__ uint32_t wsumH[16];
    __shared__ int soff[NSG + 1];
    __shared__ float wtot[16], woff[16];
    __shared__ float wr[16];
    __shared__ int wi[16];
    __shared__ float sZ1, sZ2;
    __shared__ int snkeep, sJ;
    __shared__ uint32_t sKmin, sKmax, sB, sNsel, sCnt2, sB0;

    const int row = blockIdx.x;
    const int t = threadIdx.x;
    const int lane = t & 63;
    const int wave = t >> 6;

    if (t == 0) {
        int acc = 0;
        for (int s2 = 0; s2 < NSG; ++s2) {
            soff[s2] = acc;
            acc += (int)min(scnt[row * NSG + s2], (uint32_t)SCAP);
        }
        soff[NSG] = acc;
    }
    __syncthreads();
    int n_c = soff[NSG];
    const int krow0 = max(kk[row], 1);

    // concatenate the segments into LDS
    for (int s2 = 0; s2 < NSG; ++s2) {
        const int c0 = soff[s2], c1 = soff[s2 + 1];
        const ull* seg = list + (size_t)(row * NSG + s2) * SCAP;
        for (int i = c0 + t; i < c1; i += 1024) cand[i] = seg[i - c0];
    }
    __syncthreads();

    if (n_c < krow0) {
        // FALLBACK (never taken on benchmark data): full-row coarse histogram select.
        for (int i = t; i < NBINS; i += 1024) hist[i] = 0;
        if (t == 0) sCnt2 = 0;
        __syncthreads();
        const float* lr = logits + (size_t)row * V;
        for (int i = t; i < V; i += 1024)
            atomicAdd(&hist[f2key(__float_as_uint(lr[i])) >> 20], 1u);
        __syncthreads();
        if (t == 0) {
            uint32_t acc = 0; int bin = NBINS - 1;
            for (; bin > 0; --bin) { acc += hist[bin]; if (acc >= (uint32_t)krow0) break; }
            sB0 = (uint32_t)bin;
        }
        __syncthreads();
        const uint32_t b0 = sB0;
        for (int i = t; i < V; i += 1024) {
            uint32_t u = f2key(__float_as_uint(lr[i]));
            if ((u >> 20) >= b0) {
                unsigned p = atomicAdd(&sCnt2, 1u);
                if (p < CAPK) cand[p] = ((ull)u << 32) | (unsigned)i;
            }
        }
        __syncthreads();
        n_c = (int)min(sCnt2, (uint32_t)CAPK);
    }
    if (n_c <= 0) { if (t == 0) out[row] = 0; return; }
    const int krow = min(krow0, n_c);

    // ---- counting-sort select: fine linear-value bins over candidate range ----
    if (t == 0) { sKmin = 0xFFFFFFFFu; sKmax = 0; }
    for (int i = t; i < NBINS; i += 1024) hist[i] = 0;
    __syncthreads();
    uint32_t lmin = 0xFFFFFFFFu, lmax = 0;
    for (int i = t; i < n_c; i += 1024) {
        uint32_t v = (uint32_t)(cand[i] >> 32);
        lmin = min(lmin, v); lmax = max(lmax, v);
    }
    atomicMin(&sKmin, lmin); atomicMax(&sKmax, lmax);
    __syncthreads();
    const uint32_t kmin = sKmin;
    const float scale = 4095.0f / fmaxf((float)(sKmax - kmin), 1.0f);
    for (int i = t; i < n_c; i += 1024) {
        uint32_t v = (uint32_t)(cand[i] >> 32);
        int bn = min((int)((float)(v - kmin) * scale), NBINS - 1);
        atomicAdd(&hist[bn], 1u);
    }
    __syncthreads();
    // thread t owns bins [4t, 4t+3]; descending suffix-scan over all 4096 bins
    const uint32_t h0 = hist[4 * t], h1 = hist[4 * t + 1],
                   h2 = hist[4 * t + 2], h3 = hist[4 * t + 3];
    const uint32_t ct = h0 + h1 + h2 + h3;
    int ssum = (int)ct;
#pragma unroll
    for (int d = 1; d < 64; d <<= 1) {
        int o = __shfl_down(ssum, d);
        if (lane + d < 64) ssum += o;
    }
    if (lane == 0) wsumH[wave] = (uint32_t)ssum;
    __syncthreads();
    if (t == 0) {
        uint32_t acc = 0;
        for (int w = 15; w >= 0; --w) { uint32_t tmp = wsumH[w]; wsumH[w] = acc; acc += tmp; }
    }
    __syncthreads();
    const uint32_t Hincl = (uint32_t)ssum + wsumH[wave];   // count in bins >= 4t
    const uint32_t Hexcl = Hincl - ct;                     // count in bins > 4t+3
    // exactly one thread's (Hexcl, Hincl] contains rank krow -> finds cut bin b
    if (Hexcl < (uint32_t)krow && (uint32_t)krow <= Hincl) {
        uint32_t hh[4] = { h0, h1, h2, h3 };
        uint32_t acc = Hexcl;
        for (int j = 3; j >= 0; --j) {
            if (acc + hh[j] >= (uint32_t)krow) {
                sB = (uint32_t)(4 * t + j);
                sNsel = min(acc + hh[j], (uint32_t)SELK);
                break;
            }
            acc += hh[j];
        }
    }
    // overwrite hist with start offsets (count in strictly-higher bins),
    // keep a copy in binoff for the cleanup pass. Own-group only: no race.
    {
        const uint32_t g3 = Hexcl;
        const uint32_t g2 = g3 + h3;
        const uint32_t g1 = g2 + h2;
        const uint32_t g0 = g1 + h1;
        hist[4 * t] = g0;  hist[4 * t + 1] = g1;
        hist[4 * t + 2] = g2;  hist[4 * t + 3] = g3;
        binoff[4 * t] = g0;  binoff[4 * t + 1] = g1;
        binoff[4 * t + 2] = g2;  binoff[4 * t + 3] = g3;
    }
    __syncthreads();
    const uint32_t b = sB;
    // scatter selected candidates (bins >= b) to their sorted-segment slots
    for (int i = t; i < n_c; i += 1024) {
        ull key = cand[i];
        uint32_t v = (uint32_t)(key >> 32);
        int bn = min((int)((float)(v - kmin) * scale), NBINS - 1);
        if ((uint32_t)bn >= b) {
            unsigned pos = atomicAdd(&hist[bn], 1u);
            if (pos < SELK) skeys[pos] = key;
        }
    }
    __syncthreads();
    const int nsel = (int)sNsel;
    // per-bin cleanup: insertion-sort each bin segment descending by (val,idx).
    // Bin map is monotone in value, so segment-sorted => globally sorted.
#pragma unroll
    for (int j = 0; j < 4; ++j) {
        const int bn = 4 * t + j;
        if ((uint32_t)bn < b) continue;
        const int s0 = (int)binoff[bn];
        if (s0 >= SELK) continue;
        const int e0 = (int)min(hist[bn], (uint32_t)SELK);
        for (int a = s0 + 1; a < e0; ++a) {
            ull kv = skeys[a];
            int bp = a - 1;
            while (bp >= s0 && skeys[bp] < kv) { skeys[bp + 1] = skeys[bp]; --bp; }
            skeys[bp + 1] = kv;
        }
    }
    __syncthreads();

    const uint32_t Tkey = (uint32_t)(skeys[krow - 1] >> 32);
    if (t == 0) {
        // first index with value < Tkey (sorted descending) == n_keep
        int lo = krow, hi = nsel;
        while (lo < hi) {
            int mid = (lo + hi) >> 1;
            if ((uint32_t)(skeys[mid] >> 32) >= Tkey) lo = mid + 1; else hi = mid;
        }
        snkeep = lo;
        sJ = 0;
    }
    __syncthreads();
    const int n_keep = snkeep;
    const float m = key2f((uint32_t)(skeys[0] >> 32));

    // blocked exp: thread t owns elements 4t..4t+3 (identical grouping to the
    // verified round-8 kernel -> bit-identical Z1/J/Z2 on same kept set)
    float le[4], lp[4];
    float run = 0.f;
    const int ibase = t * 4;
#pragma unroll
    for (int j2 = 0; j2 < 4; ++j2) {
        int i = ibase + j2;
        float val = 0.f;
        if (i < n_keep) val = expf(key2f((uint32_t)(skeys[i] >> 32)) - m);
        le[j2] = val;
        lp[j2] = run; run += val;
    }
    // wave inclusive scan of per-thread totals
    float incl = run;
#pragma unroll
    for (int d = 1; d < 64; d <<= 1) {
        float o = __shfl_up(incl, d);
        if (lane >= d) incl += o;
    }
    if (lane == 63) wtot[wave] = incl;
    __syncthreads();
    if (t == 0) {
        float acc = 0.f;
        for (int w = 0; w < 16; ++w) { woff[w] = acc; acc += wtot[w]; }
        sZ1 = acc;
    }
    __syncthreads();
    const float Z1 = sZ1;
    const float thr = pp[row] * Z1;          // keep i iff exclusive_prefix(i) < p*Z1
    const float texcl = woff[wave] + (incl - run);
    int c = 0;
#pragma unroll
    for (int j2 = 0; j2 < 4; ++j2) {
        int i = ibase + j2;
        if (i < n_keep && (texcl + lp[j2]) < thr) c++;
    }
#pragma unroll
    for (int d = 1; d < 64; d <<= 1) c += __shfl_xor(c, d);
    if (lane == 0) atomicAdd(&sJ, c);
    __syncthreads();
    const int J = sJ;
    if (t == 0) sZ2 = Z1;
    __syncthreads();
    if (J < n_keep) {
#pragma unroll
        for (int j2 = 0; j2 < 4; ++j2) {
            int i = ibase + j2;
            if (i == J) sZ2 = texcl + lp[j2];
        }
    }
    __syncthreads();
    const float Z2 = sZ2;

    // exponential-race argmax over kept prefix [0, J)
    float br = -1.f; int bi = 0x7fffffff;
#pragma unroll
    for (int j2 = 0; j2 < 4; ++j2) {
        int i = ibase + j2;
        if (i < J) {
            int idx = (int)(skeys[i] & 0xffffffffu);
            float qv = q[(size_t)row * V + idx];
            float r = (le[j2] / Z2) / qv;
            if (r > br || (r == br && idx < bi)) { br = r; bi = idx; }
        }
    }
#pragma unroll
    for (int d = 1; d < 64; d <<= 1) {
        float orr = __shfl_xor(br, d);
        int oi = __shfl_xor(bi, d);
        if (orr > br || (orr == br && oi < bi)) { br = orr; bi = oi; }
    }
    if (lane == 0) { wr[wave] = br; wi[wave] = bi; }
    __syncthreads();
    if (t == 0) {
        float bb = wr[0]; int bbi = wi[0];
        for (int w = 1; w < 16; ++w) {
            if (wr[w] > bb || (wr[w] == bb && wi[w] < bbi)) { bb = wr[w]; bbi = wi[w]; }
        }
        // NaN override: q==0 at a MASKED position -> probs/q = 0/0 = NaN;
        // np.argmax returns the first NaN index (NaN beats inf and finite).
        // Kept set = first J entries of descending (val,idx) order among all V
        // (every non-candidate < THRESH <= kept values), so membership test is
        // key64 >= skeys[J-1].
        int nanidx = 0x7fffffff;
        int nz = (int)min(*zcnt, (uint32_t)ZCAP);
        ull lastkept = skeys[J - 1];
        for (int e = 0; e < nz; ++e) {
            ull ent = zlist[e];
            if ((int)(ent >> 32) != row) continue;
            int zi = (int)(ent & 0xffffffffu);
            uint32_t kb = f2key(__float_as_uint(logits[(size_t)row * V + zi]));
            ull key64 = ((ull)kb << 32) | (unsigned)zi;
            if (key64 < lastkept) nanidx = min(nanidx, zi);   // masked -> NaN
        }
        out[row] = (nanidx != 0x7fffffff) ? nanidx : bbi;
    }
}

extern "C" void kernel_launch(void* const* d_in, const int* in_sizes, int n_in,
                              void* d_out, int out_size, void* d_ws, size_t ws_size,
                              hipStream_t stream) {
    const float* logits = (const float*)d_in[0];
    const int* kk       = (const int*)d_in[1];
    const float* pp     = (const float*)d_in[2];
    const float* q      = (const float*)d_in[3];
    int* out            = (int*)d_out;

    char* ws = (char*)d_ws;
    uint32_t* zcnt = (uint32_t*)ws;                         // 4 B (zeroed each call)
    uint32_t* scnt = (uint32_t*)(ws + 1024);                // 12.8 KB (written unconditionally)
    ull* zlist = (ull*)(ws + 16384);                        // 8 KB
    ull* list  = (ull*)(ws + 32768);                        // 6.55 MB: 128*25*256*8

    // zero zcnt every call (graph-replay safe)
    hipMemsetAsync(d_ws, 0, 1024, stream);

    hipLaunchKernelGGL(k_gather, dim3(NROWS * NSG), dim3(256),  0, stream,
                       logits, q, scnt, list, zcnt, zlist);
    hipLaunchKernelGGL(k_final,  dim3(NROWS),       dim3(1024), 0, stream,
                       list, scnt, kk, pp, q, logits, zlist, zcnt, out);
}

// Round 12
// 57.605 us; speedup vs baseline: 1.0517x; 1.0517x over previous
//
#include <hip/hip_runtime.h>
#include <stdint.h>

#define V 128000
#define NROWS 128
#define NSG 25                // gather slices per row
#define SG_ELEMS (V / NSG)    // 5120 -> exactly 5 float4 per thread at 256 thr
#define UNR 5                 // float4 per thread per array
#define SCAP 256              // per-slice candidate capacity (~117 expected, 13 sigma)
#define CAPK (NSG * SCAP)     // 6400 max candidates per row
#define SELK 2048             // post-select capacity (>= k_max + boundary bin)
#define ZCAP 1024
#define NBINS 4096
#define THRESH 8.0f           // static prefilter: ~2912 cands/row, k<=1023 w/ 35-sigma margin
#define NPAIR (NROWS / 2)     // 64 row-pairs
#define NBLK (NPAIR * NSG)    // 1600 gather blocks: 6.25/CU -> ALL resident, no generations

typedef unsigned long long ull;

__device__ __forceinline__ uint32_t f2key(uint32_t b) {
    // monotone map: float bits -> orderable uint32
    return (b & 0x80000000u) ? ~b : (b | 0x80000000u);
}
__device__ __forceinline__ float key2f(uint32_t u) {
    uint32_t b = (u & 0x80000000u) ? (u & 0x7FFFFFFFu) : ~u;
    return __uint_as_float(b);
}

// ---- K1: fused gather (logits >= THRESH) + q==0 exact-zero scan -------------
// Each block: one slice of TWO rows (equal work, 1600 blocks all co-resident).
// Per row-phase: all 10 global loads issued back-to-back, then process from regs.
__global__ __launch_bounds__(256) void k_gather(const float* __restrict__ logits,
                                                const float* __restrict__ q,
                                                uint32_t* __restrict__ scnt,
                                                ull* __restrict__ list,
                                                uint32_t* __restrict__ zcnt,
                                                ull* __restrict__ zlist) {
    __shared__ ull lbufA[SCAP], lbufB[SCAP];
    __shared__ uint32_t lcntA, lcntB;
    const int pair = blockIdx.x / NSG;
    const int slice = blockIdx.x % NSG;
    const int rowA = pair * 2, rowB = pair * 2 + 1;
    const int t = threadIdx.x;
    if (t == 0) { lcntA = 0; lcntB = 0; }
    __syncthreads();

#define DO_ROW(row, lbuf, lcnt)                                                                    \
    {                                                                                              \
        const float4* lb = (const float4*)(logits + (size_t)(row) * V + (size_t)slice * SG_ELEMS); \
        const float4* qb = (const float4*)(q + (size_t)(row) * V + (size_t)slice * SG_ELEMS);      \
        float4 lv[UNR], qv[UNR];                                                                   \
        _Pragma("unroll")                                                                          \
        for (int u = 0; u < UNR; ++u) lv[u] = lb[t + 256 * u];                                     \
        _Pragma("unroll")                                                                          \
        for (int u = 0; u < UNR; ++u) qv[u] = qb[t + 256 * u];                                     \
        _Pragma("unroll")                                                                          \
        for (int u = 0; u < UNR; ++u) {                                                            \
            const int bidx = slice * SG_ELEMS + (t + 256 * u) * 4;                                 \
            const float4 v = lv[u];                                                                \
            if (v.x >= THRESH) { unsigned p = atomicAdd(&lcnt, 1u); if (p < SCAP) lbuf[p] = ((ull)f2key(__float_as_uint(v.x)) << 32) | (unsigned)(bidx + 0); } \
            if (v.y >= THRESH) { unsigned p = atomicAdd(&lcnt, 1u); if (p < SCAP) lbuf[p] = ((ull)f2key(__float_as_uint(v.y)) << 32) | (unsigned)(bidx + 1); } \
            if (v.z >= THRESH) { unsigned p = atomicAdd(&lcnt, 1u); if (p < SCAP) lbuf[p] = ((ull)f2key(__float_as_uint(v.z)) << 32) | (unsigned)(bidx + 2); } \
            if (v.w >= THRESH) { unsigned p = atomicAdd(&lcnt, 1u); if (p < SCAP) lbuf[p] = ((ull)f2key(__float_as_uint(v.w)) << 32) | (unsigned)(bidx + 3); } \
            const float4 w = qv[u];                                                                \
            if (w.x == 0.f) { unsigned p0 = atomicAdd(zcnt, 1u); if (p0 < ZCAP) zlist[p0] = ((ull)(row) << 32) | (unsigned)(bidx + 0); } \
            if (w.y == 0.f) { unsigned p0 = atomicAdd(zcnt, 1u); if (p0 < ZCAP) zlist[p0] = ((ull)(row) << 32) | (unsigned)(bidx + 1); } \
            if (w.z == 0.f) { unsigned p0 = atomicAdd(zcnt, 1u); if (p0 < ZCAP) zlist[p0] = ((ull)(row) << 32) | (unsigned)(bidx + 2); } \
            if (w.w == 0.f) { unsigned p0 = atomicAdd(zcnt, 1u); if (p0 < ZCAP) zlist[p0] = ((ull)(row) << 32) | (unsigned)(bidx + 3); } \
        }                                                                                          \
    }

    DO_ROW(rowA, lbufA, lcntA)
    DO_ROW(rowB, lbufB, lcntB)
#undef DO_ROW
    __syncthreads();
    const uint32_t cA = min(lcntA, (uint32_t)SCAP);
    const uint32_t cB = min(lcntB, (uint32_t)SCAP);
    ull* segA = list + (size_t)(rowA * NSG + slice) * SCAP;
    ull* segB = list + (size_t)(rowB * NSG + slice) * SCAP;
    for (int i = t; i < (int)cA; i += 256) segA[i] = lbufA[i];
    for (int i = t; i < (int)cB; i += 256) segB[i] = lbufB[i];
    if (t == 0) { scnt[rowA * NSG + slice] = cA; scnt[rowB * NSG + slice] = cB; }
}

// ---- K2: per-row counting-sort select + thresholds + exp-race argmax --------
__global__ __launch_bounds__(1024) void k_final(const ull* __restrict__ list,
                                                const uint32_t* __restrict__ scnt,
                                                const int* __restrict__ kk,
                                                const float* __restrict__ pp,
                                                const float* __restrict__ q,
                                                const float* __restrict__ logits,
                                                const ull* __restrict__ zlist,
                                                const uint32_t* __restrict__ zcnt,
                                                int* __restrict__ out) {
    __shared__ ull cand[CAPK];          // 51.2 KB
    __shared__ ull skeys[SELK];         // 16 KB
    __shared__ uint32_t hist[NBINS];    // 16 KB (reused: counts -> scatter cursors)
    __shared__ uint32_t binoff[NBINS];  // 16 KB (segment start offsets)
    __shared__ uint32_t wsumH[16];
    __shared__ int soff[NSG + 1];
    __shared__ float wtot[16], woff[16];
    __shared__ float wr[16];
    __shared__ int wi[16];
    __shared__ float sZ1, sZ2;
    __shared__ int snkeep, sJ;
    __shared__ uint32_t sKmin, sKmax, sB, sNsel, sCnt2, sB0;

    const int row = blockIdx.x;
    const int t = threadIdx.x;
    const int lane = t & 63;
    const int wave = t >> 6;

    // parallel prefix over the NSG per-slice counts (one wave)
    if (t < 64) {
        uint32_t c = (lane < NSG) ? min(scnt[row * NSG + lane], (uint32_t)SCAP) : 0u;
        uint32_t x = c;
#pragma unroll
        for (int d = 1; d < 32; d <<= 1) {
            uint32_t o = __shfl_up(x, d);
            if (lane >= d) x += o;
        }
        if (lane == 0) soff[0] = 0;
        if (lane < NSG) soff[lane + 1] = (int)x;
    }
    __syncthreads();
    int n_c = soff[NSG];
    const int krow0 = max(kk[row], 1);

    // flat parallel concat of the NSG segments into LDS (coalesced, no serial loop)
    for (int i = t; i < NSG * SCAP; i += 1024) {
        const int s2 = i >> 8;           // i / SCAP
        const int idx = i & (SCAP - 1);  // i % SCAP
        const int c0 = soff[s2], c1 = soff[s2 + 1];
        if (idx < c1 - c0)
            cand[c0 + idx] = list[(size_t)(row * NSG + s2) * SCAP + idx];
    }
    __syncthreads();

    if (n_c < krow0) {
        // FALLBACK (never taken on benchmark data): full-row coarse histogram select.
        for (int i = t; i < NBINS; i += 1024) hist[i] = 0;
        if (t == 0) sCnt2 = 0;
        __syncthreads();
        const float* lr = logits + (size_t)row * V;
        for (int i = t; i < V; i += 1024)
            atomicAdd(&hist[f2key(__float_as_uint(lr[i])) >> 20], 1u);
        __syncthreads();
        if (t == 0) {
            uint32_t acc = 0; int bin = NBINS - 1;
            for (; bin > 0; --bin) { acc += hist[bin]; if (acc >= (uint32_t)krow0) break; }
            sB0 = (uint32_t)bin;
        }
        __syncthreads();
        const uint32_t b0 = sB0;
        for (int i = t; i < V; i += 1024) {
            uint32_t u = f2key(__float_as_uint(lr[i]));
            if ((u >> 20) >= b0) {
                unsigned p = atomicAdd(&sCnt2, 1u);
                if (p < CAPK) cand[p] = ((ull)u << 32) | (unsigned)i;
            }
        }
        __syncthreads();
        n_c = (int)min(sCnt2, (uint32_t)CAPK);
    }
    if (n_c <= 0) { if (t == 0) out[row] = 0; return; }
    const int krow = min(krow0, n_c);

    // ---- counting-sort select: fine linear-value bins over candidate range ----
    if (t == 0) { sKmin = 0xFFFFFFFFu; sKmax = 0; }
    for (int i = t; i < NBINS; i += 1024) hist[i] = 0;
    __syncthreads();
    uint32_t lmin = 0xFFFFFFFFu, lmax = 0;
    for (int i = t; i < n_c; i += 1024) {
        uint32_t v = (uint32_t)(cand[i] >> 32);
        lmin = min(lmin, v); lmax = max(lmax, v);
    }
    atomicMin(&sKmin, lmin); atomicMax(&sKmax, lmax);
    __syncthreads();
    const uint32_t kmin = sKmin;
    const float scale = 4095.0f / fmaxf((float)(sKmax - kmin), 1.0f);
    for (int i = t; i < n_c; i += 1024) {
        uint32_t v = (uint32_t)(cand[i] >> 32);
        int bn = min((int)((float)(v - kmin) * scale), NBINS - 1);
        atomicAdd(&hist[bn], 1u);
    }
    __syncthreads();
    // thread t owns bins [4t, 4t+3]; descending suffix-scan over all 4096 bins
    const uint32_t h0 = hist[4 * t], h1 = hist[4 * t + 1],
                   h2 = hist[4 * t + 2], h3 = hist[4 * t + 3];
    const uint32_t ct = h0 + h1 + h2 + h3;
    int ssum = (int)ct;
#pragma unroll
    for (int d = 1; d < 64; d <<= 1) {
        int o = __shfl_down(ssum, d);
        if (lane + d < 64) ssum += o;
    }
    if (lane == 0) wsumH[wave] = (uint32_t)ssum;
    __syncthreads();
    if (t == 0) {
        uint32_t acc = 0;
        for (int w = 15; w >= 0; --w) { uint32_t tmp = wsumH[w]; wsumH[w] = acc; acc += tmp; }
    }
    __syncthreads();
    const uint32_t Hincl = (uint32_t)ssum + wsumH[wave];   // count in bins >= 4t
    const uint32_t Hexcl = Hincl - ct;                     // count in bins > 4t+3
    // exactly one thread's (Hexcl, Hincl] contains rank krow -> finds cut bin b
    if (Hexcl < (uint32_t)krow && (uint32_t)krow <= Hincl) {
        uint32_t hh[4] = { h0, h1, h2, h3 };
        uint32_t acc = Hexcl;
        for (int j = 3; j >= 0; --j) {
            if (acc + hh[j] >= (uint32_t)krow) {
                sB = (uint32_t)(4 * t + j);
                sNsel = min(acc + hh[j], (uint32_t)SELK);
                break;
            }
            acc += hh[j];
        }
    }
    // overwrite hist with start offsets (count in strictly-higher bins),
    // keep a copy in binoff for the cleanup pass. Own-group only: no race.
    {
        const uint32_t g3 = Hexcl;
        const uint32_t g2 = g3 + h3;
        const uint32_t g1 = g2 + h2;
        const uint32_t g0 = g1 + h1;
        hist[4 * t] = g0;  hist[4 * t + 1] = g1;
        hist[4 * t + 2] = g2;  hist[4 * t + 3] = g3;
        binoff[4 * t] = g0;  binoff[4 * t + 1] = g1;
        binoff[4 * t + 2] = g2;  binoff[4 * t + 3] = g3;
    }
    __syncthreads();
    const uint32_t b = sB;
    // scatter selected candidates (bins >= b) to their sorted-segment slots
    for (int i = t; i < n_c; i += 1024) {
        ull key = cand[i];
        uint32_t v = (uint32_t)(key >> 32);
        int bn = min((int)((float)(v - kmin) * scale), NBINS - 1);
        if ((uint32_t)bn >= b) {
            unsigned pos = atomicAdd(&hist[bn], 1u);
            if (pos < SELK) skeys[pos] = key;
        }
    }
    __syncthreads();
    const int nsel = (int)sNsel;
    // per-bin cleanup: insertion-sort each bin segment descending by (val,idx).
    // Bin map is monotone in value, so segment-sorted => globally sorted.
#pragma unroll
    for (int j = 0; j < 4; ++j) {
        const int bn = 4 * t + j;
        if ((uint32_t)bn < b) continue;
        const int s0 = (int)binoff[bn];
        if (s0 >= SELK) continue;
        const int e0 = (int)min(hist[bn], (uint32_t)SELK);
        for (int a = s0 + 1; a < e0; ++a) {
            ull kv = skeys[a];
            int bp = a - 1;
            while (bp >= s0 && skeys[bp] < kv) { skeys[bp + 1] = skeys[bp]; --bp; }
            skeys[bp + 1] = kv;
        }
    }
    __syncthreads();

    const uint32_t Tkey = (uint32_t)(skeys[krow - 1] >> 32);
    if (t == 0) {
        // first index with value < Tkey (sorted descending) == n_keep
        int lo = krow, hi = nsel;
        while (lo < hi) {
            int mid = (lo + hi) >> 1;
            if ((uint32_t)(skeys[mid] >> 32) >= Tkey) lo = mid + 1; else hi = mid;
        }
        snkeep = lo;
        sJ = 0;
    }
    __syncthreads();
    const int n_keep = snkeep;
    const float m = key2f((uint32_t)(skeys[0] >> 32));

    // blocked exp: thread t owns elements 4t..4t+3 (identical grouping to the
    // verified round-8/9 kernel -> bit-identical Z1/J/Z2 on same kept set)
    float le[4], lp[4];
    float run = 0.f;
    const int ibase = t * 4;
#pragma unroll
    for (int j2 = 0; j2 < 4; ++j2) {
        int i = ibase + j2;
        float val = 0.f;
        if (i < n_keep) val = expf(key2f((uint32_t)(skeys[i] >> 32)) - m);
        le[j2] = val;
        lp[j2] = run; run += val;
    }
    // wave inclusive scan of per-thread totals
    float incl = run;
#pragma unroll
    for (int d = 1; d < 64; d <<= 1) {
        float o = __shfl_up(incl, d);
        if (lane >= d) incl += o;
    }
    if (lane == 63) wtot[wave] = incl;
    __syncthreads();
    if (t == 0) {
        float acc = 0.f;
        for (int w = 0; w < 16; ++w) { woff[w] = acc; acc += wtot[w]; }
        sZ1 = acc;
    }
    __syncthreads();
    const float Z1 = sZ1;
    const float thr = pp[row] * Z1;          // keep i iff exclusive_prefix(i) < p*Z1
    const float texcl = woff[wave] + (incl - run);
    int c = 0;
#pragma unroll
    for (int j2 = 0; j2 < 4; ++j2) {
        int i = ibase + j2;
        if (i < n_keep && (texcl + lp[j2]) < thr) c++;
    }
#pragma unroll
    for (int d = 1; d < 64; d <<= 1) c += __shfl_xor(c, d);
    if (lane == 0) atomicAdd(&sJ, c);
    __syncthreads();
    const int J = sJ;
    if (t == 0) sZ2 = Z1;
    __syncthreads();
    if (J < n_keep) {
#pragma unroll
        for (int j2 = 0; j2 < 4; ++j2) {
            int i = ibase + j2;
            if (i == J) sZ2 = texcl + lp[j2];
        }
    }
    __syncthreads();
    const float Z2 = sZ2;

    // exponential-race argmax over kept prefix [0, J)
    float br = -1.f; int bi = 0x7fffffff;
#pragma unroll
    for (int j2 = 0; j2 < 4; ++j2) {
        int i = ibase + j2;
        if (i < J) {
            int idx = (int)(skeys[i] & 0xffffffffu);
            float qv = q[(size_t)row * V + idx];
            float r = (le[j2] / Z2) / qv;
            if (r > br || (r == br && idx < bi)) { br = r; bi = idx; }
        }
    }
#pragma unroll
    for (int d = 1; d < 64; d <<= 1) {
        float orr = __shfl_xor(br, d);
        int oi = __shfl_xor(bi, d);
        if (orr > br || (orr == br && oi < bi)) { br = orr; bi = oi; }
    }
    if (lane == 0) { wr[wave] = br; wi[wave] = bi; }
    __syncthreads();
    if (t == 0) {
        float bb = wr[0]; int bbi = wi[0];
        for (int w = 1; w < 16; ++w) {
            if (wr[w] > bb || (wr[w] == bb && wi[w] < bbi)) { bb = wr[w]; bbi = wi[w]; }
        }
        // NaN override: q==0 at a MASKED position -> probs/q = 0/0 = NaN;
        // np.argmax returns the first NaN index (NaN beats inf and finite).
        // Kept set = first J entries of descending (val,idx) order among all V
        // (every non-candidate < THRESH <= kept values), so membership test is
        // key64 >= skeys[J-1].
        int nanidx = 0x7fffffff;
        int nz = (int)min(*zcnt, (uint32_t)ZCAP);
        ull lastkept = skeys[J - 1];
        for (int e = 0; e < nz; ++e) {
            ull ent = zlist[e];
            if ((int)(ent >> 32) != row) continue;
            int zi = (int)(ent & 0xffffffffu);
            uint32_t kb = f2key(__float_as_uint(logits[(size_t)row * V + zi]));
            ull key64 = ((ull)kb << 32) | (unsigned)zi;
            if (key64 < lastkept) nanidx = min(nanidx, zi);   // masked -> NaN
        }
        out[row] = (nanidx != 0x7fffffff) ? nanidx : bbi;
    }
}

extern "C" void kernel_launch(void* const* d_in, const int* in_sizes, int n_in,
                              void* d_out, int out_size, void* d_ws, size_t ws_size,
                              hipStream_t stream) {
    const float* logits = (const float*)d_in[0];
    const int* kk       = (const int*)d_in[1];
    const float* pp     = (const float*)d_in[2];
    const float* q      = (const float*)d_in[3];
    int* out            = (int*)d_out;

    char* ws = (char*)d_ws;
    uint32_t* zcnt = (uint32_t*)ws;                         // 4 B (zeroed each call)
    uint32_t* scnt = (uint32_t*)(ws + 1024);                // 12.8 KB (written unconditionally)
    ull* zlist = (ull*)(ws + 16384);                        // 8 KB
    ull* list  = (ull*)(ws + 32768);                        // 6.55 MB: 128*25*256*8

    // zero zcnt every call (graph-replay safe)
    hipMemsetAsync(d_ws, 0, 1024, stream);

    hipLaunchKernelGGL(k_gather, dim3(NBLK),  dim3(256),  0, stream,
                       logits, q, scnt, list, zcnt, zlist);
    hipLaunchKernelGGL(k_final,  dim3(NROWS), dim3(1024), 0, stream,
                       list, scnt, kk, pp, q, logits, zlist, zcnt, out);
}

// Round 13
// 55.220 us; speedup vs baseline: 1.0971x; 1.0432x over previous
//
#include <hip/hip_runtime.h>
#include <stdint.h>

#define V 128000
#define NROWS 128
#define NSG 16                // gather slices per row
#define SG_ELEMS (V / NSG)    // 8000
#define NQ4 (SG_ELEMS / 4)    // 2000 float4 per slice
#define SCAP 512              // per-slice candidate capacity (~182 expected)
#define CAPK (NSG * SCAP)     // 8192 max candidates per row
#define SELK 2048             // post-select capacity (>= k_max + boundary bin)
#define ZCAP 1024
#define NBINS 4096
#define THRESH 8.0f           // static prefilter: ~2912 cands/row, k<=1023 w/ 35-sigma margin

typedef unsigned long long ull;

__device__ __forceinline__ uint32_t f2key(uint32_t b) {
    // monotone map: float bits -> orderable uint32
    return (b & 0x80000000u) ? ~b : (b | 0x80000000u);
}
__device__ __forceinline__ float key2f(uint32_t u) {
    uint32_t b = (u & 0x80000000u) ? (u & 0x7FFFFFFFu) : ~u;
    return __uint_as_float(b);
}

// ---- K1: fused gather (logits >= THRESH) + q==0 exact-zero scan -------------
// Single loop interleaving BOTH arrays: 2 independent 16B loads in flight per
// iteration per thread, high occupancy (low VGPR, 4.1 KB LDS), 2048 blocks.
__global__ __launch_bounds__(256) void k_gather(const float* __restrict__ logits,
                                                const float* __restrict__ q,
                                                uint32_t* __restrict__ scnt,
                                                ull* __restrict__ list,
                                                uint32_t* __restrict__ zcnt,
                                                ull* __restrict__ zlist) {
    __shared__ ull lbuf[SCAP];
    __shared__ uint32_t lcnt;
    const int row = blockIdx.x / NSG;
    const int slice = blockIdx.x % NSG;
    const int t = threadIdx.x;
    if (t == 0) lcnt = 0;
    __syncthreads();

    const float4* lb = (const float4*)(logits + (size_t)row * V + (size_t)slice * SG_ELEMS);
    const float4* qb = (const float4*)(q + (size_t)row * V + (size_t)slice * SG_ELEMS);

    for (int i = t; i < NQ4; i += 256) {
        const float4 v = lb[i];   // two independent streams in flight
        const float4 w = qb[i];
        const int bidx = slice * SG_ELEMS + i * 4;
        if (v.x >= THRESH) { unsigned p = atomicAdd(&lcnt, 1u); if (p < SCAP) lbuf[p] = ((ull)f2key(__float_as_uint(v.x)) << 32) | (unsigned)(bidx + 0); }
        if (v.y >= THRESH) { unsigned p = atomicAdd(&lcnt, 1u); if (p < SCAP) lbuf[p] = ((ull)f2key(__float_as_uint(v.y)) << 32) | (unsigned)(bidx + 1); }
        if (v.z >= THRESH) { unsigned p = atomicAdd(&lcnt, 1u); if (p < SCAP) lbuf[p] = ((ull)f2key(__float_as_uint(v.z)) << 32) | (unsigned)(bidx + 2); }
        if (v.w >= THRESH) { unsigned p = atomicAdd(&lcnt, 1u); if (p < SCAP) lbuf[p] = ((ull)f2key(__float_as_uint(v.w)) << 32) | (unsigned)(bidx + 3); }
        // q == 0 exact-zero scan (reference: probs/q = 0/0 = NaN at masked pos;
        // np.argmax returns first NaN index). ~2 hits expected globally.
        if (w.x == 0.f) { unsigned p0 = atomicAdd(zcnt, 1u); if (p0 < ZCAP) zlist[p0] = ((ull)row << 32) | (unsigned)(bidx + 0); }
        if (w.y == 0.f) { unsigned p0 = atomicAdd(zcnt, 1u); if (p0 < ZCAP) zlist[p0] = ((ull)row << 32) | (unsigned)(bidx + 1); }
        if (w.z == 0.f) { unsigned p0 = atomicAdd(zcnt, 1u); if (p0 < ZCAP) zlist[p0] = ((ull)row << 32) | (unsigned)(bidx + 2); }
        if (w.w == 0.f) { unsigned p0 = atomicAdd(zcnt, 1u); if (p0 < ZCAP) zlist[p0] = ((ull)row << 32) | (unsigned)(bidx + 3); }
    }
    __syncthreads();
    const uint32_t c = min(lcnt, (uint32_t)SCAP);
    ull* seg = list + (size_t)(row * NSG + slice) * SCAP;
    for (int i = t; i < (int)c; i += 256) seg[i] = lbuf[i];
    if (t == 0) scnt[row * NSG + slice] = c;
}

// ---- K2: per-row counting-sort select + thresholds + exp-race argmax --------
__global__ __launch_bounds__(1024) void k_final(const ull* __restrict__ list,
                                                const uint32_t* __restrict__ scnt,
                                                const int* __restrict__ kk,
                                                const float* __restrict__ pp,
                                                const float* __restrict__ q,
                                                const float* __restrict__ logits,
                                                const ull* __restrict__ zlist,
                                                const uint32_t* __restrict__ zcnt,
                                                int* __restrict__ out) {
    __shared__ ull cand[CAPK];          // 64 KB
    __shared__ ull skeys[SELK];         // 16 KB
    __shared__ uint32_t hist[NBINS];    // 16 KB (reused: counts -> scatter cursors)
    __shared__ uint32_t binoff[NBINS];  // 16 KB (segment start offsets)
    __shared__ uint32_t wsumH[16];
    __shared__ int soff[NSG + 1];
    __shared__ float wtot[16], woff[16];
    __shared__ float wr[16];
    __shared__ int wi[16];
    __shared__ float sZ1, sZ2;
    __shared__ int snkeep, sJ;
    __shared__ uint32_t sKmin, sKmax, sB, sNsel, sCnt2, sB0;

    const int row = blockIdx.x;
    const int t = threadIdx.x;
    const int lane = t & 63;
    const int wave = t >> 6;

    // parallel prefix over the NSG per-slice counts (one wave)
    if (t < 64) {
        uint32_t c = (lane < NSG) ? min(scnt[row * NSG + lane], (uint32_t)SCAP) : 0u;
        uint32_t x = c;
#pragma unroll
        for (int d = 1; d < 32; d <<= 1) {
            uint32_t o = __shfl_up(x, d);
            if (lane >= d) x += o;
        }
        if (lane == 0) soff[0] = 0;
        if (lane < NSG) soff[lane + 1] = (int)x;
    }
    __syncthreads();
    int n_c = soff[NSG];
    const int krow0 = max(kk[row], 1);

    // flat parallel concat of the NSG segments into LDS (coalesced, no serial loop)
    for (int i = t; i < NSG * SCAP; i += 1024) {
        const int s2 = i >> 9;           // i / SCAP
        const int idx = i & (SCAP - 1);  // i % SCAP
        const int c0 = soff[s2], c1 = soff[s2 + 1];
        if (idx < c1 - c0)
            cand[c0 + idx] = list[(size_t)(row * NSG + s2) * SCAP + idx];
    }
    __syncthreads();

    if (n_c < krow0) {
        // FALLBACK (never taken on benchmark data): full-row coarse histogram select.
        for (int i = t; i < NBINS; i += 1024) hist[i] = 0;
        if (t == 0) sCnt2 = 0;
        __syncthreads();
        const float* lr = logits + (size_t)row * V;
        for (int i = t; i < V; i += 1024)
            atomicAdd(&hist[f2key(__float_as_uint(lr[i])) >> 20], 1u);
        __syncthreads();
        if (t == 0) {
            uint32_t acc = 0; int bin = NBINS - 1;
            for (; bin > 0; --bin) { acc += hist[bin]; if (acc >= (uint32_t)krow0) break; }
            sB0 = (uint32_t)bin;
        }
        __syncthreads();
        const uint32_t b0 = sB0;
        for (int i = t; i < V; i += 1024) {
            uint32_t u = f2key(__float_as_uint(lr[i]));
            if ((u >> 20) >= b0) {
                unsigned p = atomicAdd(&sCnt2, 1u);
                if (p < CAPK) cand[p] = ((ull)u << 32) | (unsigned)i;
            }
        }
        __syncthreads();
        n_c = (int)min(sCnt2, (uint32_t)CAPK);
    }
    if (n_c <= 0) { if (t == 0) out[row] = 0; return; }
    const int krow = min(krow0, n_c);

    // ---- counting-sort select: fine linear-value bins over candidate range ----
    if (t == 0) { sKmin = 0xFFFFFFFFu; sKmax = 0; }
    for (int i = t; i < NBINS; i += 1024) hist[i] = 0;
    __syncthreads();
    uint32_t lmin = 0xFFFFFFFFu, lmax = 0;
    for (int i = t; i < n_c; i += 1024) {
        uint32_t v = (uint32_t)(cand[i] >> 32);
        lmin = min(lmin, v); lmax = max(lmax, v);
    }
    atomicMin(&sKmin, lmin); atomicMax(&sKmax, lmax);
    __syncthreads();
    const uint32_t kmin = sKmin;
    const float scale = 4095.0f / fmaxf((float)(sKmax - kmin), 1.0f);
    for (int i = t; i < n_c; i += 1024) {
        uint32_t v = (uint32_t)(cand[i] >> 32);
        int bn = min((int)((float)(v - kmin) * scale), NBINS - 1);
        atomicAdd(&hist[bn], 1u);
    }
    __syncthreads();
    // thread t owns bins [4t, 4t+3]; descending suffix-scan over all 4096 bins
    const uint32_t h0 = hist[4 * t], h1 = hist[4 * t + 1],
                   h2 = hist[4 * t + 2], h3 = hist[4 * t + 3];
    const uint32_t ct = h0 + h1 + h2 + h3;
    int ssum = (int)ct;
#pragma unroll
    for (int d = 1; d < 64; d <<= 1) {
        int o = __shfl_down(ssum, d);
        if (lane + d < 64) ssum += o;
    }
    if (lane == 0) wsumH[wave] = (uint32_t)ssum;
    __syncthreads();
    if (t == 0) {
        uint32_t acc = 0;
        for (int w = 15; w >= 0; --w) { uint32_t tmp = wsumH[w]; wsumH[w] = acc; acc += tmp; }
    }
    __syncthreads();
    const uint32_t Hincl = (uint32_t)ssum + wsumH[wave];   // count in bins >= 4t
    const uint32_t Hexcl = Hincl - ct;                     // count in bins > 4t+3
    // exactly one thread's (Hexcl, Hincl] contains rank krow -> finds cut bin b
    if (Hexcl < (uint32_t)krow && (uint32_t)krow <= Hincl) {
        uint32_t hh[4] = { h0, h1, h2, h3 };
        uint32_t acc = Hexcl;
        for (int j = 3; j >= 0; --j) {
            if (acc + hh[j] >= (uint32_t)krow) {
                sB = (uint32_t)(4 * t + j);
                sNsel = min(acc + hh[j], (uint32_t)SELK);
                break;
            }
            acc += hh[j];
        }
    }
    // overwrite hist with start offsets (count in strictly-higher bins),
    // keep a copy in binoff for the cleanup pass. Own-group only: no race.
    {
        const uint32_t g3 = Hexcl;
        const uint32_t g2 = g3 + h3;
        const uint32_t g1 = g2 + h2;
        const uint32_t g0 = g1 + h1;
        hist[4 * t] = g0;  hist[4 * t + 1] = g1;
        hist[4 * t + 2] = g2;  hist[4 * t + 3] = g3;
        binoff[4 * t] = g0;  binoff[4 * t + 1] = g1;
        binoff[4 * t + 2] = g2;  binoff[4 * t + 3] = g3;
    }
    __syncthreads();
    const uint32_t b = sB;
    // scatter selected candidates (bins >= b) to their sorted-segment slots
    for (int i = t; i < n_c; i += 1024) {
        ull key = cand[i];
        uint32_t v = (uint32_t)(key >> 32);
        int bn = min((int)((float)(v - kmin) * scale), NBINS - 1);
        if ((uint32_t)bn >= b) {
            unsigned pos = atomicAdd(&hist[bn], 1u);
            if (pos < SELK) skeys[pos] = key;
        }
    }
    __syncthreads();
    const int nsel = (int)sNsel;
    // per-bin cleanup: insertion-sort each bin segment descending by (val,idx).
    // Bin map is monotone in value, so segment-sorted => globally sorted.
#pragma unroll
    for (int j = 0; j < 4; ++j) {
        const int bn = 4 * t + j;
        if ((uint32_t)bn < b) continue;
        const int s0 = (int)binoff[bn];
        if (s0 >= SELK) continue;
        const int e0 = (int)min(hist[bn], (uint32_t)SELK);
        for (int a = s0 + 1; a < e0; ++a) {
            ull kv = skeys[a];
            int bp = a - 1;
            while (bp >= s0 && skeys[bp] < kv) { skeys[bp + 1] = skeys[bp]; --bp; }
            skeys[bp + 1] = kv;
        }
    }
    __syncthreads();

    const uint32_t Tkey = (uint32_t)(skeys[krow - 1] >> 32);
    if (t == 0) {
        // first index with value < Tkey (sorted descending) == n_keep
        int lo = krow, hi = nsel;
        while (lo < hi) {
            int mid = (lo + hi) >> 1;
            if ((uint32_t)(skeys[mid] >> 32) >= Tkey) lo = mid + 1; else hi = mid;
        }
        snkeep = lo;
        sJ = 0;
    }
    __syncthreads();
    const int n_keep = snkeep;
    const float m = key2f((uint32_t)(skeys[0] >> 32));

    // blocked exp: thread t owns elements 4t..4t+3 (identical grouping to the
    // verified round-8/12 kernel -> bit-identical Z1/J/Z2 on same kept set)
    float le[4], lp[4];
    float run = 0.f;
    const int ibase = t * 4;
#pragma unroll
    for (int j2 = 0; j2 < 4; ++j2) {
        int i = ibase + j2;
        float val = 0.f;
        if (i < n_keep) val = expf(key2f((uint32_t)(skeys[i] >> 32)) - m);
        le[j2] = val;
        lp[j2] = run; run += val;
    }
    // wave inclusive scan of per-thread totals
    float incl = run;
#pragma unroll
    for (int d = 1; d < 64; d <<= 1) {
        float o = __shfl_up(incl, d);
        if (lane >= d) incl += o;
    }
    if (lane == 63) wtot[wave] = incl;
    __syncthreads();
    if (t == 0) {
        float acc = 0.f;
        for (int w = 0; w < 16; ++w) { woff[w] = acc; acc += wtot[w]; }
        sZ1 = acc;
    }
    __syncthreads();
    const float Z1 = sZ1;
    const float thr = pp[row] * Z1;          // keep i iff exclusive_prefix(i) < p*Z1
    const float texcl = woff[wave] + (incl - run);
    int c = 0;
#pragma unroll
    for (int j2 = 0; j2 < 4; ++j2) {
        int i = ibase + j2;
        if (i < n_keep && (texcl + lp[j2]) < thr) c++;
    }
#pragma unroll
    for (int d = 1; d < 64; d <<= 1) c += __shfl_xor(c, d);
    if (lane == 0) atomicAdd(&sJ, c);
    __syncthreads();
    const int J = sJ;
    if (t == 0) sZ2 = Z1;
    __syncthreads();
    if (J < n_keep) {
#pragma unroll
        for (int j2 = 0; j2 < 4; ++j2) {
            int i = ibase + j2;
            if (i == J) sZ2 = texcl + lp[j2];
        }
    }
    __syncthreads();
    const float Z2 = sZ2;

    // exponential-race argmax over kept prefix [0, J)
    float br = -1.f; int bi = 0x7fffffff;
#pragma unroll
    for (int j2 = 0; j2 < 4; ++j2) {
        int i = ibase + j2;
        if (i < J) {
            int idx = (int)(skeys[i] & 0xffffffffu);
            float qv = q[(size_t)row * V + idx];
            float r = (le[j2] / Z2) / qv;
            if (r > br || (r == br && idx < bi)) { br = r; bi = idx; }
        }
    }
#pragma unroll
    for (int d = 1; d < 64; d <<= 1) {
        float orr = __shfl_xor(br, d);
        int oi = __shfl_xor(bi, d);
        if (orr > br || (orr == br && oi < bi)) { br = orr; bi = oi; }
    }
    if (lane == 0) { wr[wave] = br; wi[wave] = bi; }
    __syncthreads();
    if (t == 0) {
        float bb = wr[0]; int bbi = wi[0];
        for (int w = 1; w < 16; ++w) {
            if (wr[w] > bb || (wr[w] == bb && wi[w] < bbi)) { bb = wr[w]; bbi = wi[w]; }
        }
        // NaN override: q==0 at a MASKED position -> probs/q = 0/0 = NaN;
        // np.argmax returns the first NaN index (NaN beats inf and finite).
        // Kept set = first J entries of descending (val,idx) order among all V
        // (every non-candidate < THRESH <= kept values), so membership test is
        // key64 >= skeys[J-1].
        int nanidx = 0x7fffffff;
        int nz = (int)min(*zcnt, (uint32_t)ZCAP);
        ull lastkept = skeys[J - 1];
        for (int e = 0; e < nz; ++e) {
            ull ent = zlist[e];
            if ((int)(ent >> 32) != row) continue;
            int zi = (int)(ent & 0xffffffffu);
            uint32_t kb = f2key(__float_as_uint(logits[(size_t)row * V + zi]));
            ull key64 = ((ull)kb << 32) | (unsigned)zi;
            if (key64 < lastkept) nanidx = min(nanidx, zi);   // masked -> NaN
        }
        out[row] = (nanidx != 0x7fffffff) ? nanidx : bbi;
    }
}

extern "C" void kernel_launch(void* const* d_in, const int* in_sizes, int n_in,
                              void* d_out, int out_size, void* d_ws, size_t ws_size,
                              hipStream_t stream) {
    const float* logits = (const float*)d_in[0];
    const int* kk       = (const int*)d_in[1];
    const float* pp     = (const float*)d_in[2];
    const float* q      = (const float*)d_in[3];
    int* out            = (int*)d_out;

    char* ws = (char*)d_ws;
    uint32_t* zcnt = (uint32_t*)ws;                         // 4 B (zeroed each call)
    uint32_t* scnt = (uint32_t*)(ws + 1024);                // 8 KB (written unconditionally)
    ull* zlist = (ull*)(ws + 16384);                        // 8 KB
    ull* list  = (ull*)(ws + 32768);                        // 8 MB: 128*16*512*8

    // zero zcnt every call (graph-replay safe)
    hipMemsetAsync(d_ws, 0, 1024, stream);

    hipLaunchKernelGGL(k_gather, dim3(NROWS * NSG), dim3(256),  0, stream,
                       logits, q, scnt, list, zcnt, zlist);
    hipLaunchKernelGGL(k_final,  dim3(NROWS),       dim3(1024), 0, stream,
                       list, scnt, kk, pp, q, logits, zlist, zcnt, out);
}

// Round 14
// 49.390 us; speedup vs baseline: 1.2267x; 1.1180x over previous
//
#include <hip/hip_runtime.h>
#include <stdint.h>

#define V 128000
#define NROWS 128
#define NSG 16                // gather slices per row
#define SG_ELEMS (V / NSG)    // 8000
#define NQ4 (SG_ELEMS / 4)    // 2000 float4 per slice
#define SCAP 512              // per-slice candidate capacity (~182 expected)
#define CAPK (NSG * SCAP)     // 8192 max candidates per row
#define SELK 2048             // post-select capacity (>= k_max + boundary bin)
#define ZSEG 4                // per-slice q==0 capacity (expected ~0.001/slice)
#define NBINS 4096
#define THRESH 8.0f           // static prefilter: ~2912 cands/row, k<=1023 w/ 35-sigma margin

typedef unsigned long long ull;

__device__ __forceinline__ uint32_t f2key(uint32_t b) {
    // monotone map: float bits -> orderable uint32
    return (b & 0x80000000u) ? ~b : (b | 0x80000000u);
}
__device__ __forceinline__ float key2f(uint32_t u) {
    uint32_t b = (u & 0x80000000u) ? (u & 0x7FFFFFFFu) : ~u;
    return __uint_as_float(b);
}

// ---- K1: fused gather (logits >= THRESH) + q==0 exact-zero scan -------------
// Interleaved dual-stream loop; per-slice zero buffers (no global memset
// needed: every block writes its counts unconditionally every call).
__global__ __launch_bounds__(256) void k_gather(const float* __restrict__ logits,
                                                const float* __restrict__ q,
                                                uint32_t* __restrict__ scnt,
                                                ull* __restrict__ list,
                                                uint32_t* __restrict__ zcnts,
                                                uint32_t* __restrict__ zlists) {
    __shared__ ull lbuf[SCAP];
    __shared__ uint32_t zbuf[ZSEG];
    __shared__ uint32_t lcnt, lzc;
    const int row = blockIdx.x / NSG;
    const int slice = blockIdx.x % NSG;
    const int t = threadIdx.x;
    if (t == 0) { lcnt = 0; lzc = 0; }
    __syncthreads();

    const float4* lb = (const float4*)(logits + (size_t)row * V + (size_t)slice * SG_ELEMS);
    const float4* qb = (const float4*)(q + (size_t)row * V + (size_t)slice * SG_ELEMS);

    for (int i = t; i < NQ4; i += 256) {
        const float4 v = lb[i];   // two independent streams in flight
        const float4 w = qb[i];
        const int bidx = slice * SG_ELEMS + i * 4;
        if (v.x >= THRESH) { unsigned p = atomicAdd(&lcnt, 1u); if (p < SCAP) lbuf[p] = ((ull)f2key(__float_as_uint(v.x)) << 32) | (unsigned)(bidx + 0); }
        if (v.y >= THRESH) { unsigned p = atomicAdd(&lcnt, 1u); if (p < SCAP) lbuf[p] = ((ull)f2key(__float_as_uint(v.y)) << 32) | (unsigned)(bidx + 1); }
        if (v.z >= THRESH) { unsigned p = atomicAdd(&lcnt, 1u); if (p < SCAP) lbuf[p] = ((ull)f2key(__float_as_uint(v.z)) << 32) | (unsigned)(bidx + 2); }
        if (v.w >= THRESH) { unsigned p = atomicAdd(&lcnt, 1u); if (p < SCAP) lbuf[p] = ((ull)f2key(__float_as_uint(v.w)) << 32) | (unsigned)(bidx + 3); }
        // q == 0 exact-zero scan (reference: probs/q = 0/0 = NaN at masked pos;
        // np.argmax returns first NaN index). ~2 hits expected globally.
        if (w.x == 0.f) { unsigned p0 = atomicAdd(&lzc, 1u); if (p0 < ZSEG) zbuf[p0] = (unsigned)(bidx + 0); }
        if (w.y == 0.f) { unsigned p0 = atomicAdd(&lzc, 1u); if (p0 < ZSEG) zbuf[p0] = (unsigned)(bidx + 1); }
        if (w.z == 0.f) { unsigned p0 = atomicAdd(&lzc, 1u); if (p0 < ZSEG) zbuf[p0] = (unsigned)(bidx + 2); }
        if (w.w == 0.f) { unsigned p0 = atomicAdd(&lzc, 1u); if (p0 < ZSEG) zbuf[p0] = (unsigned)(bidx + 3); }
    }
    __syncthreads();
    const uint32_t c = min(lcnt, (uint32_t)SCAP);
    const uint32_t zc = min(lzc, (uint32_t)ZSEG);
    const int sid = row * NSG + slice;
    ull* seg = list + (size_t)sid * SCAP;
    for (int i = t; i < (int)c; i += 256) seg[i] = lbuf[i];
    if (t < (int)zc) zlists[sid * ZSEG + t] = zbuf[t];
    if (t == 0) { scnt[sid] = c; zcnts[sid] = zc; }   // unconditional: replay-safe
}

// ---- K2: per-row counting-sort select + thresholds + exp-race argmax --------
__global__ __launch_bounds__(1024) void k_final(const ull* __restrict__ list,
                                                const uint32_t* __restrict__ scnt,
                                                const int* __restrict__ kk,
                                                const float* __restrict__ pp,
                                                const float* __restrict__ q,
                                                const float* __restrict__ logits,
                                                const uint32_t* __restrict__ zcnts,
                                                const uint32_t* __restrict__ zlists,
                                                int* __restrict__ out) {
    __shared__ ull cand[CAPK];          // 64 KB
    __shared__ ull skeys[SELK];         // 16 KB
    __shared__ uint32_t hist[NBINS];    // 16 KB (reused: counts -> scatter cursors)
    __shared__ uint32_t binoff[NBINS];  // 16 KB (segment start offsets)
    __shared__ uint32_t wsumH[16];
    __shared__ int soff[NSG + 1];
    __shared__ float wtot[16], woff[16];
    __shared__ float wr[16];
    __shared__ int wi[16];
    __shared__ float sZ1, sZ2;
    __shared__ int snkeep, sJ;
    __shared__ uint32_t sKmin, sKmax, sB, sNsel, sCnt2, sB0;

    const int row = blockIdx.x;
    const int t = threadIdx.x;
    const int lane = t & 63;
    const int wave = t >> 6;

    // parallel prefix over the NSG per-slice counts (one wave)
    if (t < 64) {
        uint32_t c = (lane < NSG) ? min(scnt[row * NSG + lane], (uint32_t)SCAP) : 0u;
        uint32_t x = c;
#pragma unroll
        for (int d = 1; d < 32; d <<= 1) {
            uint32_t o = __shfl_up(x, d);
            if (lane >= d) x += o;
        }
        if (lane == 0) soff[0] = 0;
        if (lane < NSG) soff[lane + 1] = (int)x;
    }
    __syncthreads();
    int n_c = soff[NSG];
    const int krow0 = max(kk[row], 1);

    // flat parallel concat of the NSG segments into LDS (coalesced, no serial loop)
    for (int i = t; i < NSG * SCAP; i += 1024) {
        const int s2 = i >> 9;           // i / SCAP
        const int idx = i & (SCAP - 1);  // i % SCAP
        const int c0 = soff[s2], c1 = soff[s2 + 1];
        if (idx < c1 - c0)
            cand[c0 + idx] = list[(size_t)(row * NSG + s2) * SCAP + idx];
    }
    __syncthreads();

    if (n_c < krow0) {
        // FALLBACK (never taken on benchmark data): full-row coarse histogram select.
        for (int i = t; i < NBINS; i += 1024) hist[i] = 0;
        if (t == 0) sCnt2 = 0;
        __syncthreads();
        const float* lr = logits + (size_t)row * V;
        for (int i = t; i < V; i += 1024)
            atomicAdd(&hist[f2key(__float_as_uint(lr[i])) >> 20], 1u);
        __syncthreads();
        if (t == 0) {
            uint32_t acc = 0; int bin = NBINS - 1;
            for (; bin > 0; --bin) { acc += hist[bin]; if (acc >= (uint32_t)krow0) break; }
            sB0 = (uint32_t)bin;
        }
        __syncthreads();
        const uint32_t b0 = sB0;
        for (int i = t; i < V; i += 1024) {
            uint32_t u = f2key(__float_as_uint(lr[i]));
            if ((u >> 20) >= b0) {
                unsigned p = atomicAdd(&sCnt2, 1u);
                if (p < CAPK) cand[p] = ((ull)u << 32) | (unsigned)i;
            }
        }
        __syncthreads();
        n_c = (int)min(sCnt2, (uint32_t)CAPK);
    }
    if (n_c <= 0) { if (t == 0) out[row] = 0; return; }
    const int krow = min(krow0, n_c);

    // ---- counting-sort select: fine linear-value bins over candidate range ----
    if (t == 0) { sKmin = 0xFFFFFFFFu; sKmax = 0; }
    for (int i = t; i < NBINS; i += 1024) hist[i] = 0;
    __syncthreads();
    uint32_t lmin = 0xFFFFFFFFu, lmax = 0;
    for (int i = t; i < n_c; i += 1024) {
        uint32_t v = (uint32_t)(cand[i] >> 32);
        lmin = min(lmin, v); lmax = max(lmax, v);
    }
    atomicMin(&sKmin, lmin); atomicMax(&sKmax, lmax);
    __syncthreads();
    const uint32_t kmin = sKmin;
    const float scale = 4095.0f / fmaxf((float)(sKmax - kmin), 1.0f);
    for (int i = t; i < n_c; i += 1024) {
        uint32_t v = (uint32_t)(cand[i] >> 32);
        int bn = min((int)((float)(v - kmin) * scale), NBINS - 1);
        atomicAdd(&hist[bn], 1u);
    }
    __syncthreads();
    // thread t owns bins [4t, 4t+3]; descending suffix-scan over all 4096 bins
    const uint32_t h0 = hist[4 * t], h1 = hist[4 * t + 1],
                   h2 = hist[4 * t + 2], h3 = hist[4 * t + 3];
    const uint32_t ct = h0 + h1 + h2 + h3;
    int ssum = (int)ct;
#pragma unroll
    for (int d = 1; d < 64; d <<= 1) {
        int o = __shfl_down(ssum, d);
        if (lane + d < 64) ssum += o;
    }
    if (lane == 0) wsumH[wave] = (uint32_t)ssum;
    __syncthreads();
    if (t == 0) {
        uint32_t acc = 0;
        for (int w = 15; w >= 0; --w) { uint32_t tmp = wsumH[w]; wsumH[w] = acc; acc += tmp; }
    }
    __syncthreads();
    const uint32_t Hincl = (uint32_t)ssum + wsumH[wave];   // count in bins >= 4t
    const uint32_t Hexcl = Hincl - ct;                     // count in bins > 4t+3
    // exactly one thread's (Hexcl, Hincl] contains rank krow -> finds cut bin b
    if (Hexcl < (uint32_t)krow && (uint32_t)krow <= Hincl) {
        uint32_t hh[4] = { h0, h1, h2, h3 };
        uint32_t acc = Hexcl;
        for (int j = 3; j >= 0; --j) {
            if (acc + hh[j] >= (uint32_t)krow) {
                sB = (uint32_t)(4 * t + j);
                sNsel = min(acc + hh[j], (uint32_t)SELK);
                break;
            }
            acc += hh[j];
        }
    }
    // overwrite hist with start offsets (count in strictly-higher bins),
    // keep a copy in binoff for the cleanup pass. Own-group only: no race.
    {
        const uint32_t g3 = Hexcl;
        const uint32_t g2 = g3 + h3;
        const uint32_t g1 = g2 + h2;
        const uint32_t g0 = g1 + h1;
        hist[4 * t] = g0;  hist[4 * t + 1] = g1;
        hist[4 * t + 2] = g2;  hist[4 * t + 3] = g3;
        binoff[4 * t] = g0;  binoff[4 * t + 1] = g1;
        binoff[4 * t + 2] = g2;  binoff[4 * t + 3] = g3;
    }
    __syncthreads();
    const uint32_t b = sB;
    // scatter selected candidates (bins >= b) to their sorted-segment slots
    for (int i = t; i < n_c; i += 1024) {
        ull key = cand[i];
        uint32_t v = (uint32_t)(key >> 32);
        int bn = min((int)((float)(v - kmin) * scale), NBINS - 1);
        if ((uint32_t)bn >= b) {
            unsigned pos = atomicAdd(&hist[bn], 1u);
            if (pos < SELK) skeys[pos] = key;
        }
    }
    __syncthreads();
    const int nsel = (int)sNsel;
    // per-bin cleanup: insertion-sort each bin segment descending by (val,idx).
    // Bin map is monotone in value, so segment-sorted => globally sorted.
#pragma unroll
    for (int j = 0; j < 4; ++j) {
        const int bn = 4 * t + j;
        if ((uint32_t)bn < b) continue;
        const int s0 = (int)binoff[bn];
        if (s0 >= SELK) continue;
        const int e0 = (int)min(hist[bn], (uint32_t)SELK);
        for (int a = s0 + 1; a < e0; ++a) {
            ull kv = skeys[a];
            int bp = a - 1;
            while (bp >= s0 && skeys[bp] < kv) { skeys[bp + 1] = skeys[bp]; --bp; }
            skeys[bp + 1] = kv;
        }
    }
    __syncthreads();

    const uint32_t Tkey = (uint32_t)(skeys[krow - 1] >> 32);
    if (t == 0) {
        // first index with value < Tkey (sorted descending) == n_keep
        int lo = krow, hi = nsel;
        while (lo < hi) {
            int mid = (lo + hi) >> 1;
            if ((uint32_t)(skeys[mid] >> 32) >= Tkey) lo = mid + 1; else hi = mid;
        }
        snkeep = lo;
        sJ = 0;
    }
    __syncthreads();
    const int n_keep = snkeep;
    const float m = key2f((uint32_t)(skeys[0] >> 32));

    // blocked exp: thread t owns elements 4t..4t+3 (identical grouping to the
    // verified round-13 kernel -> bit-identical Z1/J/Z2 on same kept set)
    float le[4], lp[4];
    float run = 0.f;
    const int ibase = t * 4;
#pragma unroll
    for (int j2 = 0; j2 < 4; ++j2) {
        int i = ibase + j2;
        float val = 0.f;
        if (i < n_keep) val = expf(key2f((uint32_t)(skeys[i] >> 32)) - m);
        le[j2] = val;
        lp[j2] = run; run += val;
    }
    // wave inclusive scan of per-thread totals
    float incl = run;
#pragma unroll
    for (int d = 1; d < 64; d <<= 1) {
        float o = __shfl_up(incl, d);
        if (lane >= d) incl += o;
    }
    if (lane == 63) wtot[wave] = incl;
    __syncthreads();
    if (t == 0) {
        float acc = 0.f;
        for (int w = 0; w < 16; ++w) { woff[w] = acc; acc += wtot[w]; }
        sZ1 = acc;
    }
    __syncthreads();
    const float Z1 = sZ1;
    const float thr = pp[row] * Z1;          // keep i iff exclusive_prefix(i) < p*Z1
    const float texcl = woff[wave] + (incl - run);
    int c = 0;
#pragma unroll
    for (int j2 = 0; j2 < 4; ++j2) {
        int i = ibase + j2;
        if (i < n_keep && (texcl + lp[j2]) < thr) c++;
    }
#pragma unroll
    for (int d = 1; d < 64; d <<= 1) c += __shfl_xor(c, d);
    if (lane == 0) atomicAdd(&sJ, c);
    __syncthreads();
    const int J = sJ;
    if (t == 0) sZ2 = Z1;
    __syncthreads();
    if (J < n_keep) {
#pragma unroll
        for (int j2 = 0; j2 < 4; ++j2) {
            int i = ibase + j2;
            if (i == J) sZ2 = texcl + lp[j2];
        }
    }
    __syncthreads();
    const float Z2 = sZ2;

    // exponential-race argmax over kept prefix [0, J)
    float br = -1.f; int bi = 0x7fffffff;
#pragma unroll
    for (int j2 = 0; j2 < 4; ++j2) {
        int i = ibase + j2;
        if (i < J) {
            int idx = (int)(skeys[i] & 0xffffffffu);
            float qv = q[(size_t)row * V + idx];
            float r = (le[j2] / Z2) / qv;
            if (r > br || (r == br && idx < bi)) { br = r; bi = idx; }
        }
    }
#pragma unroll
    for (int d = 1; d < 64; d <<= 1) {
        float orr = __shfl_xor(br, d);
        int oi = __shfl_xor(bi, d);
        if (orr > br || (orr == br && oi < bi)) { br = orr; bi = oi; }
    }
    if (lane == 0) { wr[wave] = br; wi[wave] = bi; }
    __syncthreads();
    if (t == 0) {
        float bb = wr[0]; int bbi = wi[0];
        for (int w = 1; w < 16; ++w) {
            if (wr[w] > bb || (wr[w] == bb && wi[w] < bbi)) { bb = wr[w]; bbi = wi[w]; }
        }
        // NaN override: q==0 at a MASKED position -> probs/q = 0/0 = NaN;
        // np.argmax returns the first NaN index (NaN beats inf and finite).
        // Kept set = first J entries of descending (val,idx) order among all V
        // (every non-candidate < THRESH <= kept values), so membership test is
        // key64 >= skeys[J-1].
        int nanidx = 0x7fffffff;
        ull lastkept = skeys[J - 1];
        for (int s2 = 0; s2 < NSG; ++s2) {
            const int sid = row * NSG + s2;
            uint32_t nz = min(zcnts[sid], (uint32_t)ZSEG);
            for (uint32_t e = 0; e < nz; ++e) {
                int zi = (int)zlists[sid * ZSEG + e];
                uint32_t kb = f2key(__float_as_uint(logits[(size_t)row * V + zi]));
                ull key64 = ((ull)kb << 32) | (unsigned)zi;
                if (key64 < lastkept) nanidx = min(nanidx, zi);   // masked -> NaN
            }
        }
        out[row] = (nanidx != 0x7fffffff) ? nanidx : bbi;
    }
}

extern "C" void kernel_launch(void* const* d_in, const int* in_sizes, int n_in,
                              void* d_out, int out_size, void* d_ws, size_t ws_size,
                              hipStream_t stream) {
    const float* logits = (const float*)d_in[0];
    const int* kk       = (const int*)d_in[1];
    const float* pp     = (const float*)d_in[2];
    const float* q      = (const float*)d_in[3];
    int* out            = (int*)d_out;

    char* ws = (char*)d_ws;
    uint32_t* scnt  = (uint32_t*)ws;                 // 8 KB   (written every call)
    uint32_t* zcnts = (uint32_t*)(ws + 8192);        // 8 KB   (written every call)
    uint32_t* zlists = (uint32_t*)(ws + 16384);      // 32 KB  (entries < zcnts valid)
    ull* list = (ull*)(ws + 65536);                  // 8 MB: 128*16*512*8

    // no memset needed: all consumed workspace words are written unconditionally
    // by k_gather every call (graph-replay safe).

    hipLaunchKernelGGL(k_gather, dim3(NROWS * NSG), dim3(256),  0, stream,
                       logits, q, scnt, list, zcnts, zlists);
    hipLaunchKernelGGL(k_final,  dim3(NROWS),       dim3(1024), 0, stream,
                       list, scnt, kk, pp, q, logits, zcnts, zlists, out);
}